// Round 11
// baseline (139.913 us; speedup 1.0000x reference)
//
#include <hip/hip_runtime.h>
#include <float.h>

typedef _Float16 half8 __attribute__((ext_vector_type(8)));
typedef float    f32x4 __attribute__((ext_vector_type(4)));

// Problem constants
constexpr int N_TOK = 65536;        // 16*64*64 tokens
constexpr int D     = 64;           // embedding dim
constexpr int K     = 2048;         // codebook size
constexpr int TILE_C = 64;          // codes per tile
constexpr int NTILE  = K / TILE_C;  // 32
constexpr int TOK_PER_BLK = 128;    // tokens per fused block (8 a-tiles/wave)
constexpr int NBLK = N_TOK / TOK_PER_BLK;    // 512 fused blocks
constexpr float EPS_RESCORE = 2e-3f; // belt >> pruner error (~1e-4) + key quant (~1.2e-4)

// Output layout (all float32, concatenated in reference return order)
constexpr size_t QN       = (size_t)N_TOK * D;
constexpr size_t SCAL_OFF = QN;
constexpr size_t IDX_OFF  = QN + 5;
constexpr size_t PROB_OFF = IDX_OFF + N_TOK;

// Workspace layout (bytes), total ~537 KB
constexpr size_t WS_HNORM = 0;                          // [K] f32  0.5*||c||^2
constexpr size_t WS_COUNT = 8192;                       // [K] u32
constexpr size_t WS_BSUM  = 16384;                      // [512] double
constexpr size_t WS_SW    = 24576;                      // [NTILE][256][4] half8 per-lane frag image

__device__ inline unsigned long long pack_key(float d, int k) {
    unsigned u = __float_as_uint(d);
    u = (u & 0x80000000u) ? ~u : (u | 0x80000000u);   // monotone float->uint
    return ((unsigned long long)u << 32) | (unsigned)k;
}

__device__ inline float unpack_dist(unsigned long long key) {
    unsigned u = (unsigned)(key >> 32);
    u = (u & 0x80000000u) ? (u & 0x7FFFFFFFu) : ~u;   // inverse monotone map
    return __uint_as_float(u);
}

__device__ inline unsigned long long shfl_xor_u64_w16(unsigned long long v, int m) {
    int lo = __shfl_xor((int)(unsigned)v, m, 16);
    int hi = __shfl_xor((int)(unsigned)(v >> 32), m, 16);
    return ((unsigned long long)(unsigned)hi << 32) | (unsigned)lo;
}

// One thread per (code row r, 8-elem chunk c0). Frag image: per tile, the 4
// MFMA B-fragments a consumer lane needs are CONTIGUOUS 64 B:
//   sw[(t*256 + tid)*4 + slot]  (half8), consumer tid = w*64+l, g=l>>4,
//   m16=l&15, code = t*64 + w*16 + m16,
//   slots = {hi chunk g, hi chunk g+4, lo chunk g, lo chunk g+4}.
__global__ __launch_bounds__(256) void vq_init(const float* __restrict__ emb,
                                               float* __restrict__ hnorm,
                                               unsigned* __restrict__ counts,
                                               double* __restrict__ blocksums,
                                               half8* __restrict__ sw) {
    const int g  = blockIdx.x * 256 + threadIdx.x;   // 0..16383
    const int r  = g >> 3;                           // code row
    const int c0 = g & 7;                            // chunk within row
    const float4* p4 = (const float4*)(emb + (size_t)r * D + 8 * c0);
    float4 q0 = p4[0], q1 = p4[1];
    float v[8] = {q0.x, q0.y, q0.z, q0.w, q1.x, q1.y, q1.z, q1.w};
    half8 h, l;
    float s = 0.f;
#pragma unroll
    for (int i = 0; i < 8; ++i) {
        s += v[i] * v[i];
        _Float16 hh = (_Float16)v[i];
        h[i] = hh;
        l[i] = (_Float16)(v[i] - (float)hh);
    }
    const int t    = r >> 6;
    const int w    = (r >> 4) & 3;
    const int m16  = r & 15;
    const int lane = (c0 & 3) * 16 + m16;
    const int slot = c0 >> 2;
    half8* dst = sw + ((size_t)(t * 256 + w * 64 + lane)) * 4;
    dst[slot]     = h;   // hi fragment
    dst[2 + slot] = l;   // lo fragment

#pragma unroll
    for (int off = 1; off < 8; off <<= 1) s += __shfl_xor(s, off, 8);
    if (c0 == 0) hnorm[r] = 0.5f * s;
    if (g < K) counts[g] = 0u;
    if (g < NBLK) blocksums[g] = 0.0;
}

// Load one tile's 4 contiguous B fragments + code half-norm into a named set.
#define LOADB(TOFF, P0, P1, P2, P3, HN)                                            \
  {                                                                                \
    const half8* _q = pb + (TOFF) * 1024;                                          \
    P0 = _q[0]; P1 = _q[1]; P2 = _q[2]; P3 = _q[3];                                \
    HN = ph[(TOFF) * 64];                                                          \
  }

// 8 a-tiles x 6 chained MFMAs into per-a accumulators initialized with hn:
// 48 MFMAs (~930 cy issue) against ONE 4-fragment B-load -- double the
// arithmetic intensity of the R4 structure (the R5->R4 pair isolated
// B-delivery-per-MFMA as the one lever with a clean measured gain).
// Min-tracking packs the tile index into the 5 low mantissa bits.
#define VQ_STEP(P0, P1, P2, P3, HN, TT)                                            \
  {                                                                                \
    f32x4 acc[8];                                                                  \
    __builtin_amdgcn_s_setprio(1);                                                 \
    _Pragma("unroll")                                                              \
    for (int a = 0; a < 8; ++a) {                                                  \
      acc[a] = (f32x4){(HN), (HN), (HN), (HN)};                                    \
      acc[a] = __builtin_amdgcn_mfma_f32_16x16x32_f16(axh[a][0], P0, acc[a], 0, 0, 0); \
      acc[a] = __builtin_amdgcn_mfma_f32_16x16x32_f16(axh[a][1], P1, acc[a], 0, 0, 0); \
      acc[a] = __builtin_amdgcn_mfma_f32_16x16x32_f16(axl[a][0], P0, acc[a], 0, 0, 0); \
      acc[a] = __builtin_amdgcn_mfma_f32_16x16x32_f16(axl[a][1], P1, acc[a], 0, 0, 0); \
      acc[a] = __builtin_amdgcn_mfma_f32_16x16x32_f16(axh[a][0], P2, acc[a], 0, 0, 0); \
      acc[a] = __builtin_amdgcn_mfma_f32_16x16x32_f16(axh[a][1], P3, acc[a], 0, 0, 0); \
    }                                                                              \
    __builtin_amdgcn_s_setprio(0);                                                 \
    _Pragma("unroll")                                                              \
    for (int a = 0; a < 8; ++a)                                                    \
      _Pragma("unroll")                                                            \
      for (int r = 0; r < 4; ++r) {                                                \
        unsigned _kb = (__float_as_uint(acc[a][r]) & 0xFFFFFFE0u) | (unsigned)(TT);\
        best_d[a][r] = fminf(best_d[a][r], __uint_as_float(_kb));                  \
      }                                                                            \
  }

// Fused: one block = 128 tokens x ALL 2048 codes. Barrier-free main loop,
// even/odd register double-buffer, direct global->VGPR B stream. 4 waves
// split codes (16 each); each wave owns all 128 tokens (8 a-tiles, 128 VGPR
// of A-fragments -- the (256,2) bound raises the regalloc cap; 2 waves/SIMD
// occupancy, which R5 proved is not the binding resource). Grid 512 = 2
// blocks/CU exactly fills the 2-wave/SIMD capacity.
__global__ __launch_bounds__(256, 2) void vq_fused(const float* __restrict__ x,
                                                   const float* __restrict__ emb,
                                                   const float* __restrict__ hnorm,
                                                   const half8* __restrict__ sw,
                                                   unsigned* __restrict__ counts,
                                                   double* __restrict__ blocksums,
                                                   float* __restrict__ out) {
    __shared__ unsigned long long kls[128][5];        // 4 candidates + pad
    __shared__ int bks[128];
    __shared__ double wsum[4];

    const int tid  = threadIdx.x;
    const int lane = tid & 63;
    const int wav  = tid >> 6;
    const int t0   = blockIdx.x * TOK_PER_BLK;
    const int m16  = lane & 15;             // A row (token) / B col (code)
    const int g    = lane >> 4;             // k-chunk group (0..3)
    const int ko   = g * 8;
    const int cit  = wav * 16 + m16;        // wave w owns codes [w*16, w*16+16)

    // A fragments: 8 a-tiles (the block's 128 tokens), negated hi/lo fp16 split
    half8 axh[8][2], axl[8][2];
#pragma unroll
    for (int a = 0; a < 8; ++a) {
        const float* xr = x + (size_t)(t0 + 16 * a + m16) * D;
#pragma unroll
        for (int c = 0; c < 2; ++c) {
            const float4* p4 = (const float4*)(xr + 32 * c + ko);
            float4 q0 = p4[0], q1 = p4[1];
            float v[8] = {q0.x, q0.y, q0.z, q0.w, q1.x, q1.y, q1.z, q1.w};
            half8 h, l;
#pragma unroll
            for (int j = 0; j < 8; ++j) {
                float nv = -v[j];
                _Float16 hh = (_Float16)nv;
                h[j] = hh;
                l[j] = (_Float16)(nv - (float)hh);
            }
            axh[a][c] = h; axl[a][c] = l;
        }
    }

    float best_d[8][4];                     // packed keys: dist w/ tile idx in low 5 bits
#pragma unroll
    for (int a = 0; a < 8; ++a)
#pragma unroll
        for (int r = 0; r < 4; ++r) best_d[a][r] = FLT_MAX;

    // per-lane streaming pointers: 64 B of fragments per lane per tile
    const half8* pb = sw + (size_t)tid * 4;           // tile stride = 1024 half8
    const float* ph = hnorm + cit;                    // tile stride = 64 floats

    half8 sA0, sA1, sA2, sA3;  float hA;   // even tiles
    half8 sB0, sB1, sB2, sB3;  float hB;   // odd tiles

    // prologue: tile 0
    LOADB(0, sA0, sA1, sA2, sA3, hA);

    for (int t = 0; t < NTILE; t += 2) {
        LOADB(1, sB0, sB1, sB2, sB3, hB);             // tile t+1
        VQ_STEP(sA0, sA1, sA2, sA3, hA, t);
        if (t + 2 < NTILE) LOADB(2, sA0, sA1, sA2, sA3, hA);   // tile t+2
        VQ_STEP(sB0, sB1, sB2, sB3, hB, t + 1);
        pb += 2048; ph += 128;
    }

    // recover code from packed key; col-reduce over this wave's 16 columns
#pragma unroll
    for (int a = 0; a < 8; ++a)
#pragma unroll
        for (int r = 0; r < 4; ++r) {
            const unsigned bits = __float_as_uint(best_d[a][r]);
            const int code = (int)(bits & 31u) * TILE_C + cit;
            unsigned long long key = pack_key(best_d[a][r], code);
#pragma unroll
            for (int off = 8; off; off >>= 1) {
                unsigned long long o = shfl_xor_u64_w16(key, off);
                if (o < key) key = o;
            }
            if (m16 == 0) kls[16 * a + g * 4 + r][wav] = key;
        }
    __syncthreads();

    // merge the 4 wave-winners per token (one lane per token, 128 tokens)
    if (tid < 128) {
        float ds[4]; int kk[4];
        unsigned long long kmin = ~0ULL;
#pragma unroll
        for (int w = 0; w < 4; ++w) {
            unsigned long long key = kls[tid][w];
            ds[w] = unpack_dist(key);
            kk[w] = (int)(unsigned)(key & 0xFFFFFFFFu);
            if (key < kmin) kmin = key;
        }
        int bk = (int)(unsigned)(kmin & 0xFFFFFFFFu);
        const float fmin = unpack_dist(kmin);
        int cnt = 0;
#pragma unroll
        for (int w = 0; w < 4; ++w) cnt += (ds[w] <= fmin + EPS_RESCORE) ? 1 : 0;

        if (cnt > 1) {   // rare near-tie: exact fp32 rescore; packed-key min
            unsigned long long bkey = ~0ULL;   // smaller dist, tie smaller k
            const float* xr = x + (size_t)(t0 + tid) * D;
            for (int w = 0; w < 4; ++w) {
                if (ds[w] <= fmin + EPS_RESCORE) {
                    const int k = kk[w];
                    const float* cr = emb + (size_t)k * D;
                    float s0 = 0.f, s1 = 0.f, s2 = 0.f, s3 = 0.f;
#pragma unroll
                    for (int i = 0; i < 16; ++i) {
                        s0 = fmaf(cr[4 * i + 0], xr[4 * i + 0], s0);
                        s1 = fmaf(cr[4 * i + 1], xr[4 * i + 1], s1);
                        s2 = fmaf(cr[4 * i + 2], xr[4 * i + 2], s2);
                        s3 = fmaf(cr[4 * i + 3], xr[4 * i + 3], s3);
                    }
                    float hd = hnorm[k] - ((s0 + s1) + (s2 + s3));
                    unsigned long long key = pack_key(hd, k);
                    if (key < bkey) bkey = key;
                }
            }
            bk = (int)(unsigned)(bkey & 0xFFFFFFFFu);
        }
        bks[tid] = bk;
        out[IDX_OFF + t0 + tid] = (float)bk;
        atomicAdd(&counts[bk], 1u);
    }
    __syncthreads();

    // inline epilogue: quantize + sumsq (4 threads per token, 2 passes)
    float local = 0.f;
#pragma unroll
    for (int hh = 0; hh < 2; ++hh) {
        const int tok = hh * 64 + (tid >> 2);
        const int i4  = tid & 3;
        const int bk  = bks[tok];
        const float4* xr4 = (const float4*)(x + (size_t)(t0 + tok) * D);
        const float4* cr4 = (const float4*)(emb + (size_t)bk * D);
        float4* qr4 = (float4*)(out + (size_t)(t0 + tok) * D);
#pragma unroll
        for (int ii = 0; ii < 4; ++ii) {
            const int idx = i4 + 4 * ii;
            float4 xv = xr4[idx];
            float4 cv = cr4[idx];
            float dx = cv.x - xv.x, dy = cv.y - xv.y;
            float dz = cv.z - xv.z, dw = cv.w - xv.w;
            local += dx * dx + dy * dy + dz * dz + dw * dw;
            float4 q;
            q.x = xv.x + dx; q.y = xv.y + dy;   // straight-through: x + (q - x)
            q.z = xv.z + dz; q.w = xv.w + dw;
            qr4[idx] = q;
        }
    }
    double ld = (double)local;
#pragma unroll
    for (int off = 32; off > 0; off >>= 1) ld += __shfl_down(ld, off, 64);
    if (lane == 0) wsum[wav] = ld;
    __syncthreads();
    if (tid == 0)
        blocksums[blockIdx.x] = (wsum[0] + wsum[1]) + (wsum[2] + wsum[3]);
}

__global__ __launch_bounds__(256) void vq_finalize(const unsigned* __restrict__ counts,
                                                   const double* __restrict__ blocksums,
                                                   float* __restrict__ out) {
    const int tid = threadIdx.x;
    double e = 0.0;
#pragma unroll
    for (int i = 0; i < 8; ++i) {
        int k = tid + i * 256;
        float p = (float)counts[k] / 65536.0f;
        out[PROB_OFF + k] = p;
        double pd = (double)p;
        e += pd * log(pd + 1e-5);
    }
    double s = 0.0;
#pragma unroll
    for (int i = 0; i < NBLK / 256; ++i) s += blocksums[tid + i * 256];
#pragma unroll
    for (int off = 32; off > 0; off >>= 1) {
        e += __shfl_down(e, off, 64);
        s += __shfl_down(s, off, 64);
    }
    __shared__ double we[4], ws2[4];
    int lane = tid & 63, wid = tid >> 6;
    if (lane == 0) { we[wid] = e; ws2[wid] = s; }
    __syncthreads();
    if (tid == 0) {
        double entropy = (we[0] + we[1]) + (we[2] + we[3]);
        double sumsq   = (ws2[0] + ws2[1]) + (ws2[2] + ws2[3]);
        double mse     = sumsq / (double)((size_t)N_TOK * D);
        out[SCAL_OFF + 0] = (float)(1.25 * mse + 0.1 * entropy); // vq_loss
        out[SCAL_OFF + 1] = (float)mse;                          // commitment_loss
        out[SCAL_OFF + 2] = (float)mse;                          // codebook_loss
        out[SCAL_OFF + 3] = (float)exp(-entropy);                // perplexity
        out[SCAL_OFF + 4] = (float)entropy;                      // entropy_loss
    }
}

extern "C" void kernel_launch(void* const* d_in, const int* in_sizes, int n_in,
                              void* d_out, int out_size, void* d_ws, size_t ws_size,
                              hipStream_t stream) {
    const float* x   = (const float*)d_in[0];
    const float* emb = (const float*)d_in[1];
    float* out = (float*)d_out;

    char* ws = (char*)d_ws;
    float*    hnorm     = (float*)(ws + WS_HNORM);
    unsigned* counts    = (unsigned*)(ws + WS_COUNT);
    double*   blocksums = (double*)(ws + WS_BSUM);
    half8*    sw        = (half8*)(ws + WS_SW);

    vq_init<<<K * 8 / 256, 256, 0, stream>>>(emb, hnorm, counts, blocksums, sw);
    vq_fused<<<NBLK, 256, 0, stream>>>(x, emb, hnorm, sw, counts, blocksums, out);
    vq_finalize<<<1, 256, 0, stream>>>(counts, blocksums, out);
}

// Round 12
// 132.498 us; speedup vs baseline: 1.0560x; 1.0560x over previous
//
#include <hip/hip_runtime.h>
#include <float.h>

typedef _Float16 half8 __attribute__((ext_vector_type(8)));
typedef float    f32x4 __attribute__((ext_vector_type(4)));

// Problem constants
constexpr int N_TOK = 65536;        // 16*64*64 tokens
constexpr int D     = 64;           // embedding dim
constexpr int K     = 2048;         // codebook size
constexpr int TILE_C = 64;          // codes per tile
constexpr int NTILE  = K / TILE_C;  // 32
constexpr int TOK_PER_BLK = 64;     // tokens per fused block
constexpr int NBLK = N_TOK / TOK_PER_BLK;    // 1024 fused blocks
constexpr float EPS_RESCORE = 2e-3f; // belt >> pruner error (~1e-4) + key quant (~1.2e-4)

// Output layout (all float32, concatenated in reference return order)
constexpr size_t QN       = (size_t)N_TOK * D;
constexpr size_t SCAL_OFF = QN;
constexpr size_t IDX_OFF  = QN + 5;
constexpr size_t PROB_OFF = IDX_OFF + N_TOK;

// Workspace layout (bytes), total ~680 KB
constexpr size_t WS_HNORM = 0;                          // [K] f32  0.5*||c||^2
constexpr size_t WS_COUNT = 8192;                       // [K] u32
constexpr size_t WS_BSUM  = 16384;                      // [1024] double
constexpr size_t WS_SW    = 24576;                      // [NTILE][256 rec][80 B] frag records
constexpr int REC_B  = 80;                              // 4x half8 + f32 hnorm + 12 pad
constexpr int TILE_B = 256 * REC_B;                     // 20480 B per tile

__device__ inline unsigned long long pack_key(float d, int k) {
    unsigned u = __float_as_uint(d);
    u = (u & 0x80000000u) ? ~u : (u | 0x80000000u);   // monotone float->uint
    return ((unsigned long long)u << 32) | (unsigned)k;
}

__device__ inline float unpack_dist(unsigned long long key) {
    unsigned u = (unsigned)(key >> 32);
    u = (u & 0x80000000u) ? (u & 0x7FFFFFFFu) : ~u;   // inverse monotone map
    return __uint_as_float(u);
}

__device__ inline unsigned long long shfl_xor_u64_w16(unsigned long long v, int m) {
    int lo = __shfl_xor((int)(unsigned)v, m, 16);
    int hi = __shfl_xor((int)(unsigned)(v >> 32), m, 16);
    return ((unsigned long long)(unsigned)hi << 32) | (unsigned)lo;
}

// One thread per (code row r, 8-elem chunk c0). 80-B frag record per
// (tile, consumer tid): {hi chunk g, hi chunk g+4, lo chunk g, lo chunk g+4,
// hnorm(f32), pad}. Consumer tid = w*64+l, g=l>>4, m16=l&15, code =
// t*64 + w*16 + m16 -- all four fragments and hn of record (w,l) come from
// code row r0 = t*64 + w*16 + m16. Producer (r,c0): lane=(c0&3)*16+m16,
// slot=c0>>2; threads c0<4 also write hn (butterfly gives all 8 the norm).
__global__ __launch_bounds__(256) void vq_init(const float* __restrict__ emb,
                                               float* __restrict__ hnorm,
                                               unsigned* __restrict__ counts,
                                               double* __restrict__ blocksums,
                                               char* __restrict__ swb) {
    const int g  = blockIdx.x * 256 + threadIdx.x;   // 0..16383
    const int r  = g >> 3;                           // code row
    const int c0 = g & 7;                            // chunk within row
    const float4* p4 = (const float4*)(emb + (size_t)r * D + 8 * c0);
    float4 q0 = p4[0], q1 = p4[1];
    float v[8] = {q0.x, q0.y, q0.z, q0.w, q1.x, q1.y, q1.z, q1.w};
    half8 h, l;
    float s = 0.f;
#pragma unroll
    for (int i = 0; i < 8; ++i) {
        s += v[i] * v[i];
        _Float16 hh = (_Float16)v[i];
        h[i] = hh;
        l[i] = (_Float16)(v[i] - (float)hh);
    }
    const int t    = r >> 6;
    const int w    = (r >> 4) & 3;
    const int m16  = r & 15;
    const int lane = (c0 & 3) * 16 + m16;
    const int slot = c0 >> 2;
    char* rec = swb + (size_t)(t * 256 + w * 64 + lane) * REC_B;
    *(half8*)(rec + slot * 16)       = h;   // hi fragment
    *(half8*)(rec + (2 + slot) * 16) = l;   // lo fragment

#pragma unroll
    for (int off = 1; off < 8; off <<= 1) s += __shfl_xor(s, off, 8);
    if (c0 < 4) *(float*)(rec + 64) = 0.5f * s;   // per-record hnorm
    if (c0 == 0) hnorm[r] = 0.5f * s;             // global (rescore path)
    if (g < K) counts[g] = 0u;
    if (g < NBLK) blocksums[g] = 0.0;
}

// PINNED tile load: 5 asm-volatile VMEM ops from one 80-B record pointer.
// asm volatile cannot be sunk to the use site (the compiler deleted every
// source-level prefetch across R4-R10: VGPR stuck at 92-100), so these stay
// issued 2 full VQ_STEPs before consumption. "=&v" early-clobber: loads are
// async, dests must not alias the address pair.
#define ISSUE(P0, P1, P2, P3, HN)                                                  \
  {                                                                                \
    asm volatile("global_load_dwordx4 %0, %5, off\n\t"                             \
                 "global_load_dwordx4 %1, %5, off offset:16\n\t"                   \
                 "global_load_dwordx4 %2, %5, off offset:32\n\t"                   \
                 "global_load_dwordx4 %3, %5, off offset:48\n\t"                   \
                 "global_load_dword   %4, %5, off offset:64"                       \
                 : "=&v"(P0), "=&v"(P1), "=&v"(P2), "=&v"(P3), "=&v"(HN)           \
                 : "v"(pl));                                                       \
    pl += TILE_B;                                                                  \
  }

// Counted wait: N VMEM ops may stay in flight (the 2 prefetched tiles).
// NEVER 0 in the main loop. sched_barrier(0) right after: hipcc hoists
// register-only MFMAs past inline-asm waitcnt despite clobbers (rule #18).
#define WAITC(N)                                                                   \
  asm volatile("s_waitcnt vmcnt(" #N ")" ::: "memory");                            \
  __builtin_amdgcn_sched_barrier(0);

// 6 chained MFMAs into ONE accumulator initialized with hn. MFMAs batched
// under setprio(1). Min-tracking packs the tile index into the 5 low
// mantissa bits (2 VALU/elem; perturbation <= 32 ulp ~ 1.2e-4 << belt).
#define VQ_STEP(P0, P1, P2, P3, HN, TT)                                            \
  {                                                                                \
    f32x4 acc[4];                                                                  \
    __builtin_amdgcn_s_setprio(1);                                                 \
    _Pragma("unroll")                                                              \
    for (int a = 0; a < 4; ++a) {                                                  \
      acc[a] = (f32x4){(HN), (HN), (HN), (HN)};                                    \
      acc[a] = __builtin_amdgcn_mfma_f32_16x16x32_f16(axh[a][0], P0, acc[a], 0, 0, 0); \
      acc[a] = __builtin_amdgcn_mfma_f32_16x16x32_f16(axh[a][1], P1, acc[a], 0, 0, 0); \
      acc[a] = __builtin_amdgcn_mfma_f32_16x16x32_f16(axl[a][0], P0, acc[a], 0, 0, 0); \
      acc[a] = __builtin_amdgcn_mfma_f32_16x16x32_f16(axl[a][1], P1, acc[a], 0, 0, 0); \
      acc[a] = __builtin_amdgcn_mfma_f32_16x16x32_f16(axh[a][0], P2, acc[a], 0, 0, 0); \
      acc[a] = __builtin_amdgcn_mfma_f32_16x16x32_f16(axh[a][1], P3, acc[a], 0, 0, 0); \
    }                                                                              \
    __builtin_amdgcn_s_setprio(0);                                                 \
    _Pragma("unroll")                                                              \
    for (int a = 0; a < 4; ++a)                                                    \
      _Pragma("unroll")                                                            \
      for (int r = 0; r < 4; ++r) {                                                \
        unsigned _kb = (__float_as_uint(acc[a][r]) & 0xFFFFFFE0u) | (unsigned)(TT);\
        best_d[a][r] = fminf(best_d[a][r], __uint_as_float(_kb));                  \
      }                                                                            \
  }

// Fused: one block = 64 tokens x ALL 2048 codes. Barrier-free main loop with
// a REAL depth-2 pipeline: asm-pinned loads (can't be sunk), 3 named register
// sets, counted vmcnt(10) per step (2 tiles always in flight). Invariant at
// iteration t's wait: outstanding = tiles {t+1, t+2} = 10 ops; any older ops
// (A-prologue) are forced complete by the same wait -> always safe.
__global__ __launch_bounds__(256, 2) void vq_fused(const float* __restrict__ x,
                                                   const float* __restrict__ emb,
                                                   const float* __restrict__ hnorm,
                                                   const char* __restrict__ swb,
                                                   unsigned* __restrict__ counts,
                                                   double* __restrict__ blocksums,
                                                   float* __restrict__ out) {
    __shared__ unsigned long long kls[64][5];         // 4 candidates + pad
    __shared__ int bks[64];
    __shared__ double wsum[4];

    const int tid  = threadIdx.x;
    const int lane = tid & 63;
    const int wav  = tid >> 6;
    const int t0   = blockIdx.x * TOK_PER_BLK;
    const int m16  = lane & 15;             // A row (token) / B col (code)
    const int g    = lane >> 4;             // k-chunk group (0..3)
    const int ko   = g * 8;
    const int cit  = wav * 16 + m16;        // wave w owns codes [w*16, w*16+16)

    // A fragments: 4 a-tiles (the block's 64 tokens), negated hi/lo fp16 split
    half8 axh[4][2], axl[4][2];
#pragma unroll
    for (int a = 0; a < 4; ++a) {
        const float* xr = x + (size_t)(t0 + 16 * a + m16) * D;
#pragma unroll
        for (int c = 0; c < 2; ++c) {
            const float4* p4 = (const float4*)(xr + 32 * c + ko);
            float4 q0 = p4[0], q1 = p4[1];
            float v[8] = {q0.x, q0.y, q0.z, q0.w, q1.x, q1.y, q1.z, q1.w};
            half8 h, l;
#pragma unroll
            for (int j = 0; j < 8; ++j) {
                float nv = -v[j];
                _Float16 hh = (_Float16)nv;
                h[j] = hh;
                l[j] = (_Float16)(nv - (float)hh);
            }
            axh[a][c] = h; axl[a][c] = l;
        }
    }

    float best_d[4][4];                     // packed keys: dist w/ tile idx in low 5 bits
#pragma unroll
    for (int a = 0; a < 4; ++a)
#pragma unroll
        for (int r = 0; r < 4; ++r) best_d[a][r] = FLT_MAX;

    // per-lane record pointer, advances one tile (20480 B) per ISSUE
    const char* pl = swb + (size_t)tid * REC_B;

    half8 A0, A1, A2, A3;  float hA;   // set for tiles t = 0 mod 3
    half8 B0, B1, B2, B3;  float hB;   // set for tiles t = 1 mod 3
    half8 C0, C1, C2, C3;  float hC;   // set for tiles t = 2 mod 3

    // prologue: tiles 0,1 in flight (10 VMEM ops outstanding)
    ISSUE(A0, A1, A2, A3, hA);
    ISSUE(B0, B1, B2, B3, hB);

    // main loop: t = 0,3,...,27; consumes tiles 0..29, issues through 31.
    for (int t = 0; t < 28; t += 3) {
        ISSUE(C0, C1, C2, C3, hC);          // tile t+2
        WAITC(10);                           // tile t complete
        VQ_STEP(A0, A1, A2, A3, hA, t);
        ISSUE(A0, A1, A2, A3, hA);          // tile t+3
        WAITC(10);                           // tile t+1 complete
        VQ_STEP(B0, B1, B2, B3, hB, t + 1);
        ISSUE(B0, B1, B2, B3, hB);          // tile t+4
        WAITC(10);                           // tile t+2 complete
        VQ_STEP(C0, C1, C2, C3, hC, t + 2);
    }
    // tail: tiles 30 (set A), 31 (set B)
    WAITC(5);
    VQ_STEP(A0, A1, A2, A3, hA, 30);
    WAITC(0);
    VQ_STEP(B0, B1, B2, B3, hB, 31);

    // recover code from packed key; col-reduce over this wave's 16 columns
#pragma unroll
    for (int a = 0; a < 4; ++a)
#pragma unroll
        for (int r = 0; r < 4; ++r) {
            const unsigned bits = __float_as_uint(best_d[a][r]);
            const int code = (int)(bits & 31u) * TILE_C + cit;
            unsigned long long key = pack_key(best_d[a][r], code);
#pragma unroll
            for (int off = 8; off; off >>= 1) {
                unsigned long long o = shfl_xor_u64_w16(key, off);
                if (o < key) key = o;
            }
            if (m16 == 0) kls[16 * a + g * 4 + r][wav] = key;
        }
    __syncthreads();

    // merge the 4 wave-winners per token (wave 0, one lane per token)
    if (tid < 64) {
        float ds[4]; int kk[4];
        unsigned long long kmin = ~0ULL;
#pragma unroll
        for (int w = 0; w < 4; ++w) {
            unsigned long long key = kls[tid][w];
            ds[w] = unpack_dist(key);
            kk[w] = (int)(unsigned)(key & 0xFFFFFFFFu);
            if (key < kmin) kmin = key;
        }
        int bk = (int)(unsigned)(kmin & 0xFFFFFFFFu);
        const float fmin = unpack_dist(kmin);
        int cnt = 0;
#pragma unroll
        for (int w = 0; w < 4; ++w) cnt += (ds[w] <= fmin + EPS_RESCORE) ? 1 : 0;

        if (cnt > 1) {   // rare near-tie: exact fp32 rescore; packed-key min
            unsigned long long bkey = ~0ULL;   // smaller dist, tie smaller k
            const float* xr = x + (size_t)(t0 + tid) * D;
            for (int w = 0; w < 4; ++w) {
                if (ds[w] <= fmin + EPS_RESCORE) {
                    const int k = kk[w];
                    const float* cr = emb + (size_t)k * D;
                    float s0 = 0.f, s1 = 0.f, s2 = 0.f, s3 = 0.f;
#pragma unroll
                    for (int i = 0; i < 16; ++i) {
                        s0 = fmaf(cr[4 * i + 0], xr[4 * i + 0], s0);
                        s1 = fmaf(cr[4 * i + 1], xr[4 * i + 1], s1);
                        s2 = fmaf(cr[4 * i + 2], xr[4 * i + 2], s2);
                        s3 = fmaf(cr[4 * i + 3], xr[4 * i + 3], s3);
                    }
                    float hd = hnorm[k] - ((s0 + s1) + (s2 + s3));
                    unsigned long long key = pack_key(hd, k);
                    if (key < bkey) bkey = key;
                }
            }
            bk = (int)(unsigned)(bkey & 0xFFFFFFFFu);
        }
        bks[tid] = bk;
        out[IDX_OFF + t0 + tid] = (float)bk;
        atomicAdd(&counts[bk], 1u);
    }
    __syncthreads();

    // inline epilogue: quantize + sumsq (4 threads per token, coalesced)
    const int tok = tid >> 2;
    const int i4  = tid & 3;
    const int bk  = bks[tok];
    const float4* xr4 = (const float4*)(x + (size_t)(t0 + tok) * D);
    const float4* cr4 = (const float4*)(emb + (size_t)bk * D);
    float4* qr4 = (float4*)(out + (size_t)(t0 + tok) * D);
    float local = 0.f;
#pragma unroll
    for (int ii = 0; ii < 4; ++ii) {
        const int idx = i4 + 4 * ii;
        float4 xv = xr4[idx];
        float4 cv = cr4[idx];
        float dx = cv.x - xv.x, dy = cv.y - xv.y;
        float dz = cv.z - xv.z, dw = cv.w - xv.w;
        local += dx * dx + dy * dy + dz * dz + dw * dw;
        float4 q;
        q.x = xv.x + dx; q.y = xv.y + dy;   // straight-through: x + (q - x)
        q.z = xv.z + dz; q.w = xv.w + dw;
        qr4[idx] = q;
    }
    double ld = (double)local;
#pragma unroll
    for (int off = 32; off > 0; off >>= 1) ld += __shfl_down(ld, off, 64);
    if (lane == 0) wsum[wav] = ld;
    __syncthreads();
    if (tid == 0)
        blocksums[blockIdx.x] = (wsum[0] + wsum[1]) + (wsum[2] + wsum[3]);
}

__global__ __launch_bounds__(256) void vq_finalize(const unsigned* __restrict__ counts,
                                                   const double* __restrict__ blocksums,
                                                   float* __restrict__ out) {
    const int tid = threadIdx.x;
    double e = 0.0;
#pragma unroll
    for (int i = 0; i < 8; ++i) {
        int k = tid + i * 256;
        float p = (float)counts[k] / 65536.0f;
        out[PROB_OFF + k] = p;
        double pd = (double)p;
        e += pd * log(pd + 1e-5);
    }
    double s = 0.0;
#pragma unroll
    for (int i = 0; i < NBLK / 256; ++i) s += blocksums[tid + i * 256];
#pragma unroll
    for (int off = 32; off > 0; off >>= 1) {
        e += __shfl_down(e, off, 64);
        s += __shfl_down(s, off, 64);
    }
    __shared__ double we[4], ws2[4];
    int lane = tid & 63, wid = tid >> 6;
    if (lane == 0) { we[wid] = e; ws2[wid] = s; }
    __syncthreads();
    if (tid == 0) {
        double entropy = (we[0] + we[1]) + (we[2] + we[3]);
        double sumsq   = (ws2[0] + ws2[1]) + (ws2[2] + ws2[3]);
        double mse     = sumsq / (double)((size_t)N_TOK * D);
        out[SCAL_OFF + 0] = (float)(1.25 * mse + 0.1 * entropy); // vq_loss
        out[SCAL_OFF + 1] = (float)mse;                          // commitment_loss
        out[SCAL_OFF + 2] = (float)mse;                          // codebook_loss
        out[SCAL_OFF + 3] = (float)exp(-entropy);                // perplexity
        out[SCAL_OFF + 4] = (float)entropy;                      // entropy_loss
    }
}

extern "C" void kernel_launch(void* const* d_in, const int* in_sizes, int n_in,
                              void* d_out, int out_size, void* d_ws, size_t ws_size,
                              hipStream_t stream) {
    const float* x   = (const float*)d_in[0];
    const float* emb = (const float*)d_in[1];
    float* out = (float*)d_out;

    char* ws = (char*)d_ws;
    float*    hnorm     = (float*)(ws + WS_HNORM);
    unsigned* counts    = (unsigned*)(ws + WS_COUNT);
    double*   blocksums = (double*)(ws + WS_BSUM);
    char*     swb       = ws + WS_SW;

    vq_init<<<K * 8 / 256, 256, 0, stream>>>(emb, hnorm, counts, blocksums, swb);
    vq_fused<<<NBLK, 256, 0, stream>>>(x, emb, hnorm, swb, counts, blocksums, out);
    vq_finalize<<<1, 256, 0, stream>>>(counts, blocksums, out);
}

// Round 13
// 130.567 us; speedup vs baseline: 1.0716x; 1.0148x over previous
//
#include <hip/hip_runtime.h>
#include <float.h>

typedef _Float16 half8 __attribute__((ext_vector_type(8)));
typedef float    f32x4 __attribute__((ext_vector_type(4)));

// Problem constants
constexpr int N_TOK = 65536;        // 16*64*64 tokens
constexpr int D     = 64;           // embedding dim
constexpr int K     = 2048;         // codebook size
constexpr int TILE_C = 64;          // codes per tile
constexpr int NTILE  = K / TILE_C;  // 32
constexpr int TOK_PER_BLK = 64;     // tokens per fused block
constexpr int NBLK = N_TOK / TOK_PER_BLK;    // 1024 fused blocks
// hh-only coarse distances: err = sum(xh*cl + xl*ch) ~ sigma 3.2e-3.
// Belt = 0.15 (~47 sigma, same x50 margin the old 2e-3/4e-5 pair had).
// Near-min candidate density ~0.09/unit -> E[in-belt] ~ 1.01 per token;
// cnt>1 (exact fp32 rescore) fires for ~1.3% of tokens.
constexpr float EPS_RESCORE = 0.15f;

// Output layout (all float32, concatenated in reference return order)
constexpr size_t QN       = (size_t)N_TOK * D;
constexpr size_t SCAL_OFF = QN;
constexpr size_t IDX_OFF  = QN + 5;
constexpr size_t PROB_OFF = IDX_OFF + N_TOK;

// Workspace layout (bytes), total ~352 KB
constexpr size_t WS_HNORM = 0;                          // [K] f32  0.5*||c||^2
constexpr size_t WS_COUNT = 8192;                       // [K] u32
constexpr size_t WS_BSUM  = 16384;                      // [1024] double
constexpr size_t WS_SW    = 24576;                      // [NTILE][256 rec][40 B] hi-frag records
constexpr int REC_B  = 40;                              // 2x half8 (hi) + f32 hnorm + 4 pad
constexpr int TILE_B = 256 * REC_B;                     // 10240 B per tile

__device__ inline unsigned long long pack_key(float d, int k) {
    unsigned u = __float_as_uint(d);
    u = (u & 0x80000000u) ? ~u : (u | 0x80000000u);   // monotone float->uint
    return ((unsigned long long)u << 32) | (unsigned)k;
}

__device__ inline float unpack_dist(unsigned long long key) {
    unsigned u = (unsigned)(key >> 32);
    u = (u & 0x80000000u) ? (u & 0x7FFFFFFFu) : ~u;   // inverse monotone map
    return __uint_as_float(u);
}

__device__ inline unsigned long long shfl_xor_u64_w16(unsigned long long v, int m) {
    int lo = __shfl_xor((int)(unsigned)v, m, 16);
    int hi = __shfl_xor((int)(unsigned)(v >> 32), m, 16);
    return ((unsigned long long)(unsigned)hi << 32) | (unsigned)lo;
}

// One thread per (code row r, 8-elem chunk c0). 40-B record per (tile,
// consumer tid): {hi chunk g, hi chunk g+4, hnorm(f32), pad}. Consumer
// tid = w*64+l (g=l>>4, m16=l&15, code = t*64 + w*16 + m16). Producer
// (r,c0): lane=(c0&3)*16+m16, slot=c0>>2 (chunk c0<4 -> P0, else P1);
// the c0<4 thread also writes hn after the 8-way butterfly.
__global__ __launch_bounds__(256) void vq_init(const float* __restrict__ emb,
                                               float* __restrict__ hnorm,
                                               unsigned* __restrict__ counts,
                                               double* __restrict__ blocksums,
                                               char* __restrict__ swb) {
    const int g  = blockIdx.x * 256 + threadIdx.x;   // 0..16383
    const int r  = g >> 3;                           // code row
    const int c0 = g & 7;                            // chunk within row
    const float4* p4 = (const float4*)(emb + (size_t)r * D + 8 * c0);
    float4 q0 = p4[0], q1 = p4[1];
    float v[8] = {q0.x, q0.y, q0.z, q0.w, q1.x, q1.y, q1.z, q1.w};
    half8 h;
    float s = 0.f;
#pragma unroll
    for (int i = 0; i < 8; ++i) {
        s += v[i] * v[i];
        h[i] = (_Float16)v[i];
    }
    const int t    = r >> 6;
    const int w    = (r >> 4) & 3;
    const int m16  = r & 15;
    const int lane = (c0 & 3) * 16 + m16;
    const int slot = c0 >> 2;
    char* rec = swb + (size_t)(t * 256 + w * 64 + lane) * REC_B;
    *(half8*)(rec + slot * 16) = h;   // hi fragment (P0 or P1)

#pragma unroll
    for (int off = 1; off < 8; off <<= 1) s += __shfl_xor(s, off, 8);
    if (c0 < 4) *(float*)(rec + 32) = 0.5f * s;   // per-record hnorm
    if (c0 == 0) hnorm[r] = 0.5f * s;             // global (rescore path)
    if (g < K) counts[g] = 0u;
    if (g < NBLK) blocksums[g] = 0.0;
}

// PINNED tile load: 3 asm-volatile VMEM ops from one 40-B record pointer
// (asm cannot be sunk -> the depth-2 pipeline survives regalloc, proven R12).
#define ISSUE(P0, P1, HN)                                                          \
  {                                                                                \
    asm volatile("global_load_dwordx4 %0, %3, off\n\t"                             \
                 "global_load_dwordx4 %1, %3, off offset:16\n\t"                   \
                 "global_load_dword   %2, %3, off offset:32"                       \
                 : "=&v"(P0), "=&v"(P1), "=&v"(HN)                                 \
                 : "v"(pl));                                                       \
    pl += TILE_B;                                                                  \
  }

// Counted wait (never 0 in main loop) + sched_barrier (rule #18: hipcc
// hoists register-only MFMAs past inline-asm waitcnt).
#define WAITC(N)                                                                   \
  asm volatile("s_waitcnt vmcnt(" #N ")" ::: "memory");                            \
  __builtin_amdgcn_sched_barrier(0);

// hh-only coarse step: 2 MFMAs per a-tile (8 total, was 24). Per-lane TOP-2
// min tracking (3 VALU/val): with err sigma ~3e-3 the true argmin can lose a
// within-lane race, so rank-2 must survive to the merge. Tile idx packed in
// the 5 low mantissa bits (<=32 ulp ~ 4.9e-4 << belt).
#define VQ_STEP(P0, P1, HN, TT)                                                    \
  {                                                                                \
    f32x4 acc[4];                                                                  \
    __builtin_amdgcn_s_setprio(1);                                                 \
    _Pragma("unroll")                                                              \
    for (int a = 0; a < 4; ++a) {                                                  \
      acc[a] = (f32x4){(HN), (HN), (HN), (HN)};                                    \
      acc[a] = __builtin_amdgcn_mfma_f32_16x16x32_f16(axh[a][0], P0, acc[a], 0, 0, 0); \
      acc[a] = __builtin_amdgcn_mfma_f32_16x16x32_f16(axh[a][1], P1, acc[a], 0, 0, 0); \
    }                                                                              \
    __builtin_amdgcn_s_setprio(0);                                                 \
    _Pragma("unroll")                                                              \
    for (int a = 0; a < 4; ++a)                                                    \
      _Pragma("unroll")                                                            \
      for (int r = 0; r < 4; ++r) {                                                \
        unsigned _kb = (__float_as_uint(acc[a][r]) & 0xFFFFFFE0u) | (unsigned)(TT);\
        float _f = __uint_as_float(_kb);                                           \
        best2[a][r] = fminf(best2[a][r], fmaxf(best1[a][r], _f));                  \
        best1[a][r] = fminf(best1[a][r], _f);                                      \
      }                                                                            \
  }

// Fused: one block = 64 tokens x ALL 2048 codes. hh-only coarse scan with
// top-2 tracking; exact fp32 rescore for the rare in-belt near-ties. R12's
// asm-pinned barrier-free depth-2 pipeline (3 named sets, vmcnt(6)).
__global__ __launch_bounds__(256, 2) void vq_fused(const float* __restrict__ x,
                                                   const float* __restrict__ emb,
                                                   const float* __restrict__ hnorm,
                                                   const char* __restrict__ swb,
                                                   unsigned* __restrict__ counts,
                                                   double* __restrict__ blocksums,
                                                   float* __restrict__ out) {
    __shared__ unsigned long long kls[64][10];        // 8 candidates + pad
    __shared__ int bks[64];
    __shared__ double wsum[4];

    const int tid  = threadIdx.x;
    const int lane = tid & 63;
    const int wav  = tid >> 6;
    const int t0   = blockIdx.x * TOK_PER_BLK;
    const int m16  = lane & 15;             // A row (token) / B col (code)
    const int g    = lane >> 4;             // k-chunk group (0..3)
    const int ko   = g * 8;
    const int cit  = wav * 16 + m16;        // wave w owns codes [w*16, w*16+16)

    // A fragments: 4 a-tiles, hi (negated fp16) only -- no lo needed now
    half8 axh[4][2];
#pragma unroll
    for (int a = 0; a < 4; ++a) {
        const float* xr = x + (size_t)(t0 + 16 * a + m16) * D;
#pragma unroll
        for (int c = 0; c < 2; ++c) {
            const float4* p4 = (const float4*)(xr + 32 * c + ko);
            float4 q0 = p4[0], q1 = p4[1];
            float v[8] = {q0.x, q0.y, q0.z, q0.w, q1.x, q1.y, q1.z, q1.w};
            half8 h;
#pragma unroll
            for (int j = 0; j < 8; ++j) h[j] = (_Float16)(-v[j]);
            axh[a][c] = h;
        }
    }

    float best1[4][4], best2[4][4];         // packed keys, top-2 per lane
#pragma unroll
    for (int a = 0; a < 4; ++a)
#pragma unroll
        for (int r = 0; r < 4; ++r) { best1[a][r] = FLT_MAX; best2[a][r] = FLT_MAX; }

    // per-lane record pointer, advances one tile (10240 B) per ISSUE
    const char* pl = swb + (size_t)tid * REC_B;

    half8 A0, A1;  float hA;   // set for tiles t = 0 mod 3
    half8 B0, B1;  float hB;   // set for tiles t = 1 mod 3
    half8 C0, C1;  float hC;   // set for tiles t = 2 mod 3

    // prologue: tiles 0,1 in flight (6 VMEM ops outstanding)
    ISSUE(A0, A1, hA);
    ISSUE(B0, B1, hB);

    // main loop: t = 0,3,...,27; consumes tiles 0..29, issues through 31.
    for (int t = 0; t < 28; t += 3) {
        ISSUE(C0, C1, hC);                  // tile t+2
        WAITC(6);                            // tile t complete
        VQ_STEP(A0, A1, hA, t);
        ISSUE(A0, A1, hA);                  // tile t+3
        WAITC(6);                            // tile t+1 complete
        VQ_STEP(B0, B1, hB, t + 1);
        ISSUE(B0, B1, hB);                  // tile t+4
        WAITC(6);                            // tile t+2 complete
        VQ_STEP(C0, C1, hC, t + 2);
    }
    // tail: tiles 30 (set A), 31 (set B)
    WAITC(3);
    VQ_STEP(A0, A1, hA, 30);
    WAITC(0);
    VQ_STEP(B0, B1, hB, 31);

    // recover codes; TOP-2 butterfly over the 16-lane column group:
    // merge two sorted pairs per stage -> group's two smallest keys.
#pragma unroll
    for (int a = 0; a < 4; ++a)
#pragma unroll
        for (int r = 0; r < 4; ++r) {
            const unsigned b1 = __float_as_uint(best1[a][r]);
            const unsigned b2 = __float_as_uint(best2[a][r]);
            unsigned long long k1 = pack_key(best1[a][r], (int)(b1 & 31u) * TILE_C + cit);
            unsigned long long k2 = pack_key(best2[a][r], (int)(b2 & 31u) * TILE_C + cit);
#pragma unroll
            for (int off = 8; off; off >>= 1) {
                unsigned long long o1 = shfl_xor_u64_w16(k1, off);
                unsigned long long o2 = shfl_xor_u64_w16(k2, off);
                unsigned long long hi1 = (k1 > o1) ? k1 : o1;
                unsigned long long lo2 = (k2 < o2) ? k2 : o2;
                k1 = (k1 < o1) ? k1 : o1;
                k2 = (hi1 < lo2) ? hi1 : lo2;
            }
            if (m16 == 0) {
                kls[16 * a + g * 4 + r][wav]     = k1;
                kls[16 * a + g * 4 + r][4 + wav] = k2;
            }
        }
    __syncthreads();

    // merge 8 candidates per token (wave 0, one lane per token)
    if (tid < 64) {
        float ds[8]; int kk[8];
        unsigned long long kmin = ~0ULL;
#pragma unroll
        for (int w = 0; w < 8; ++w) {
            unsigned long long key = kls[tid][w];
            ds[w] = unpack_dist(key);
            kk[w] = (int)(unsigned)(key & 0xFFFFFFFFu);
            if (key < kmin) kmin = key;
        }
        int bk = (int)(unsigned)(kmin & 0xFFFFFFFFu);
        const float fmin = unpack_dist(kmin);
        int cnt = 0;
#pragma unroll
        for (int w = 0; w < 8; ++w) cnt += (ds[w] <= fmin + EPS_RESCORE) ? 1 : 0;

        if (cnt > 1) {   // near-tie in the coarse metric: exact fp32 rescore
            unsigned long long bkey = ~0ULL;   // smaller dist, tie smaller k
            const float* xr = x + (size_t)(t0 + tid) * D;
            for (int w = 0; w < 8; ++w) {
                if (ds[w] <= fmin + EPS_RESCORE) {
                    const int k = kk[w];
                    const float* cr = emb + (size_t)k * D;
                    float s0 = 0.f, s1 = 0.f, s2 = 0.f, s3 = 0.f;
#pragma unroll
                    for (int i = 0; i < 16; ++i) {
                        s0 = fmaf(cr[4 * i + 0], xr[4 * i + 0], s0);
                        s1 = fmaf(cr[4 * i + 1], xr[4 * i + 1], s1);
                        s2 = fmaf(cr[4 * i + 2], xr[4 * i + 2], s2);
                        s3 = fmaf(cr[4 * i + 3], xr[4 * i + 3], s3);
                    }
                    float hd = hnorm[k] - ((s0 + s1) + (s2 + s3));
                    unsigned long long key = pack_key(hd, k);
                    if (key < bkey) bkey = key;
                }
            }
            bk = (int)(unsigned)(bkey & 0xFFFFFFFFu);
        }
        bks[tid] = bk;
        out[IDX_OFF + t0 + tid] = (float)bk;
        atomicAdd(&counts[bk], 1u);
    }
    __syncthreads();

    // inline epilogue: quantize + sumsq (4 threads per token, coalesced)
    const int tok = tid >> 2;
    const int i4  = tid & 3;
    const int bk  = bks[tok];
    const float4* xr4 = (const float4*)(x + (size_t)(t0 + tok) * D);
    const float4* cr4 = (const float4*)(emb + (size_t)bk * D);
    float4* qr4 = (float4*)(out + (size_t)(t0 + tok) * D);
    float local = 0.f;
#pragma unroll
    for (int ii = 0; ii < 4; ++ii) {
        const int idx = i4 + 4 * ii;
        float4 xv = xr4[idx];
        float4 cv = cr4[idx];
        float dx = cv.x - xv.x, dy = cv.y - xv.y;
        float dz = cv.z - xv.z, dw = cv.w - xv.w;
        local += dx * dx + dy * dy + dz * dz + dw * dw;
        float4 q;
        q.x = xv.x + dx; q.y = xv.y + dy;   // straight-through: x + (q - x)
        q.z = xv.z + dz; q.w = xv.w + dw;
        qr4[idx] = q;
    }
    double ld = (double)local;
#pragma unroll
    for (int off = 32; off > 0; off >>= 1) ld += __shfl_down(ld, off, 64);
    if (lane == 0) wsum[wav] = ld;
    __syncthreads();
    if (tid == 0)
        blocksums[blockIdx.x] = (wsum[0] + wsum[1]) + (wsum[2] + wsum[3]);
}

__global__ __launch_bounds__(256) void vq_finalize(const unsigned* __restrict__ counts,
                                                   const double* __restrict__ blocksums,
                                                   float* __restrict__ out) {
    const int tid = threadIdx.x;
    double e = 0.0;
#pragma unroll
    for (int i = 0; i < 8; ++i) {
        int k = tid + i * 256;
        float p = (float)counts[k] / 65536.0f;
        out[PROB_OFF + k] = p;
        double pd = (double)p;
        e += pd * log(pd + 1e-5);
    }
    double s = 0.0;
#pragma unroll
    for (int i = 0; i < NBLK / 256; ++i) s += blocksums[tid + i * 256];
#pragma unroll
    for (int off = 32; off > 0; off >>= 1) {
        e += __shfl_down(e, off, 64);
        s += __shfl_down(s, off, 64);
    }
    __shared__ double we[4], ws2[4];
    int lane = tid & 63, wid = tid >> 6;
    if (lane == 0) { we[wid] = e; ws2[wid] = s; }
    __syncthreads();
    if (tid == 0) {
        double entropy = (we[0] + we[1]) + (we[2] + we[3]);
        double sumsq   = (ws2[0] + ws2[1]) + (ws2[2] + ws2[3]);
        double mse     = sumsq / (double)((size_t)N_TOK * D);
        out[SCAL_OFF + 0] = (float)(1.25 * mse + 0.1 * entropy); // vq_loss
        out[SCAL_OFF + 1] = (float)mse;                          // commitment_loss
        out[SCAL_OFF + 2] = (float)mse;                          // codebook_loss
        out[SCAL_OFF + 3] = (float)exp(-entropy);                // perplexity
        out[SCAL_OFF + 4] = (float)entropy;                      // entropy_loss
    }
}

extern "C" void kernel_launch(void* const* d_in, const int* in_sizes, int n_in,
                              void* d_out, int out_size, void* d_ws, size_t ws_size,
                              hipStream_t stream) {
    const float* x   = (const float*)d_in[0];
    const float* emb = (const float*)d_in[1];
    float* out = (float*)d_out;

    char* ws = (char*)d_ws;
    float*    hnorm     = (float*)(ws + WS_HNORM);
    unsigned* counts    = (unsigned*)(ws + WS_COUNT);
    double*   blocksums = (double*)(ws + WS_BSUM);
    char*     swb       = ws + WS_SW;

    vq_init<<<K * 8 / 256, 256, 0, stream>>>(emb, hnorm, counts, blocksums, swb);
    vq_fused<<<NBLK, 256, 0, stream>>>(x, emb, hnorm, swb, counts, blocksums, out);
    vq_finalize<<<1, 256, 0, stream>>>(counts, blocksums, out);
}

// Round 14
// 128.980 us; speedup vs baseline: 1.0848x; 1.0123x over previous
//
#include <hip/hip_runtime.h>
#include <float.h>

typedef _Float16 half8 __attribute__((ext_vector_type(8)));
typedef float    f32x4 __attribute__((ext_vector_type(4)));

// Problem constants
constexpr int N_TOK = 65536;        // 16*64*64 tokens
constexpr int D     = 64;           // embedding dim
constexpr int K     = 2048;         // codebook size
constexpr int TILE_C = 64;          // codes per tile
constexpr int NTILE  = K / TILE_C;  // 32
constexpr int TOK_PER_BLK = 64;     // tokens per fused block
constexpr int NBLK = N_TOK / TOK_PER_BLK;    // 1024 fused blocks
// hh-only coarse distances: err ~ sigma 3.2e-3; belt 0.15 ~ 47 sigma.
// E[in-belt] ~ 1.01/token; exact-rescore path fires ~1.3% of tokens.
constexpr float EPS_RESCORE = 0.15f;

// Output layout (all float32, concatenated in reference return order)
constexpr size_t QN       = (size_t)N_TOK * D;
constexpr size_t SCAL_OFF = QN;
constexpr size_t IDX_OFF  = QN + 5;
constexpr size_t PROB_OFF = IDX_OFF + N_TOK;

// Workspace layout (bytes), total ~352 KB
constexpr size_t WS_HNORM = 0;                          // [K] f32  0.5*||c||^2
constexpr size_t WS_COUNT = 8192;                       // [K] u32
constexpr size_t WS_BSUM  = 16384;                      // [1024] double
constexpr size_t WS_SW    = 24576;                      // [NTILE][256 rec][40 B] hi-frag records
constexpr int REC_B  = 40;                              // 2x half8 (hi) + f32 hnorm + 4 pad
constexpr int TILE_B = 256 * REC_B;                     // 10240 B per tile

__device__ inline unsigned long long pack_key(float d, int k) {
    unsigned u = __float_as_uint(d);
    u = (u & 0x80000000u) ? ~u : (u | 0x80000000u);   // monotone float->uint
    return ((unsigned long long)u << 32) | (unsigned)k;
}

__device__ inline float unpack_dist(unsigned long long key) {
    unsigned u = (unsigned)(key >> 32);
    u = (u & 0x80000000u) ? (u & 0x7FFFFFFFu) : ~u;   // inverse monotone map
    return __uint_as_float(u);
}

__device__ inline unsigned long long shfl_xor_u64_w16(unsigned long long v, int m) {
    int lo = __shfl_xor((int)(unsigned)v, m, 16);
    int hi = __shfl_xor((int)(unsigned)(v >> 32), m, 16);
    return ((unsigned long long)(unsigned)hi << 32) | (unsigned)lo;
}

// One thread per (code row r, 8-elem chunk c0). 40-B record per (tile,
// consumer tid): {hi chunk g, hi chunk g+4, hnorm(f32), pad}. Consumer
// tid = w*64+l (g=l>>4, m16=l&15, code = t*64 + w*16 + m16). Producer
// (r,c0): lane=(c0&3)*16+m16, slot=c0>>2; c0<4 thread writes hn after the
// 8-way butterfly.
__global__ __launch_bounds__(256) void vq_init(const float* __restrict__ emb,
                                               float* __restrict__ hnorm,
                                               unsigned* __restrict__ counts,
                                               double* __restrict__ blocksums,
                                               char* __restrict__ swb) {
    const int g  = blockIdx.x * 256 + threadIdx.x;   // 0..16383
    const int r  = g >> 3;                           // code row
    const int c0 = g & 7;                            // chunk within row
    const float4* p4 = (const float4*)(emb + (size_t)r * D + 8 * c0);
    float4 q0 = p4[0], q1 = p4[1];
    float v[8] = {q0.x, q0.y, q0.z, q0.w, q1.x, q1.y, q1.z, q1.w};
    half8 h;
    float s = 0.f;
#pragma unroll
    for (int i = 0; i < 8; ++i) {
        s += v[i] * v[i];
        h[i] = (_Float16)v[i];
    }
    const int t    = r >> 6;
    const int w    = (r >> 4) & 3;
    const int m16  = r & 15;
    const int lane = (c0 & 3) * 16 + m16;
    const int slot = c0 >> 2;
    char* rec = swb + (size_t)(t * 256 + w * 64 + lane) * REC_B;
    *(half8*)(rec + slot * 16) = h;   // hi fragment (P0 or P1)

#pragma unroll
    for (int off = 1; off < 8; off <<= 1) s += __shfl_xor(s, off, 8);
    if (c0 < 4) *(float*)(rec + 32) = 0.5f * s;   // per-record hnorm
    if (c0 == 0) hnorm[r] = 0.5f * s;             // global (rescore path)
    if (g < K) counts[g] = 0u;
    if (g < NBLK) blocksums[g] = 0.0;
}

// PINNED tile load, saddr form: per-lane voffset is FIXED (tid*40); the
// uniform tile base lives in an SGPR pair and advances via SALU in C --
// removes the per-lane 64-bit pointer adds from the hot loop. asm volatile
// cannot be sunk (R12-proven), so the depth-3 pipeline survives regalloc.
#define ISSUE(P0, P1, HN, SB)                                                      \
  asm volatile("global_load_dwordx4 %0, %3, %4\n\t"                                \
               "global_load_dwordx4 %1, %3, %4 offset:16\n\t"                      \
               "global_load_dword   %2, %3, %4 offset:32"                          \
               : "=&v"(P0), "=&v"(P1), "=&v"(HN)                                   \
               : "v"(voff), "s"(SB));

// Counted wait (never 0 in main loop) + sched_barrier (rule #18: hipcc
// hoists register-only MFMAs past inline-asm waitcnt).
#define WAITC(N)                                                                   \
  asm volatile("s_waitcnt vmcnt(" #N ")" ::: "memory");                            \
  __builtin_amdgcn_sched_barrier(0);

// hh-only coarse step: 8 MFMAs. Top-2 min tracking via v_med3_f32:
// given b1<=b2, median(b1,b2,f) IS the new second-best -> 3 VALU/value
// (and_or + med3 + min), down from 4. No setprio (lockstep regime: null
// per m190). Tile idx packed in the 5 low mantissa bits.
#define VQ_STEP(P0, P1, HN, TT)                                                    \
  {                                                                                \
    f32x4 acc[4];                                                                  \
    _Pragma("unroll")                                                              \
    for (int a = 0; a < 4; ++a) {                                                  \
      acc[a] = (f32x4){(HN), (HN), (HN), (HN)};                                    \
      acc[a] = __builtin_amdgcn_mfma_f32_16x16x32_f16(axh[a][0], P0, acc[a], 0, 0, 0); \
      acc[a] = __builtin_amdgcn_mfma_f32_16x16x32_f16(axh[a][1], P1, acc[a], 0, 0, 0); \
    }                                                                              \
    _Pragma("unroll")                                                              \
    for (int a = 0; a < 4; ++a)                                                    \
      _Pragma("unroll")                                                            \
      for (int r = 0; r < 4; ++r) {                                                \
        unsigned _kb = (__float_as_uint(acc[a][r]) & 0xFFFFFFE0u) | (unsigned)(TT);\
        float _f = __uint_as_float(_kb);                                           \
        best2[a][r] = __builtin_amdgcn_fmed3f(best1[a][r], best2[a][r], _f);       \
        best1[a][r] = fminf(best1[a][r], _f);                                      \
      }                                                                            \
  }

// Fused: one block = 64 tokens x ALL 2048 codes. hh-only coarse scan,
// top-2 tracking, exact fp32 rescore for in-belt near-ties. Barrier-free
// asm-pinned DEPTH-3 pipeline: 4 named sets, vmcnt(9) (3 tiles in flight).
__global__ __launch_bounds__(256, 2) void vq_fused(const float* __restrict__ x,
                                                   const float* __restrict__ emb,
                                                   const float* __restrict__ hnorm,
                                                   const char* __restrict__ swb,
                                                   unsigned* __restrict__ counts,
                                                   double* __restrict__ blocksums,
                                                   float* __restrict__ out) {
    __shared__ unsigned long long kls[64][10];        // 8 candidates + pad
    __shared__ int bks[64];
    __shared__ double wsum[4];

    const int tid  = threadIdx.x;
    const int lane = tid & 63;
    const int wav  = tid >> 6;
    const int t0   = blockIdx.x * TOK_PER_BLK;
    const int m16  = lane & 15;             // A row (token) / B col (code)
    const int g    = lane >> 4;             // k-chunk group (0..3)
    const int ko   = g * 8;
    const int cit  = wav * 16 + m16;        // wave w owns codes [w*16, w*16+16)

    // A fragments: 4 a-tiles, hi (negated fp16) only
    half8 axh[4][2];
#pragma unroll
    for (int a = 0; a < 4; ++a) {
        const float* xr = x + (size_t)(t0 + 16 * a + m16) * D;
#pragma unroll
        for (int c = 0; c < 2; ++c) {
            const float4* p4 = (const float4*)(xr + 32 * c + ko);
            float4 q0 = p4[0], q1 = p4[1];
            float v[8] = {q0.x, q0.y, q0.z, q0.w, q1.x, q1.y, q1.z, q1.w};
            half8 h;
#pragma unroll
            for (int j = 0; j < 8; ++j) h[j] = (_Float16)(-v[j]);
            axh[a][c] = h;
        }
    }

    float best1[4][4], best2[4][4];         // packed keys, top-2 per lane
#pragma unroll
    for (int a = 0; a < 4; ++a)
#pragma unroll
        for (int r = 0; r < 4; ++r) { best1[a][r] = FLT_MAX; best2[a][r] = FLT_MAX; }

    // fixed per-lane offset + uniform SGPR tile base (advances via SALU)
    const unsigned voff = (unsigned)(tid * REC_B);
    unsigned long long sb = (unsigned long long)swb;

    half8 A0, A1;  float hA;   // tiles t = 0 mod 4
    half8 B0, B1;  float hB;   // tiles t = 1 mod 4
    half8 C0, C1;  float hC;   // tiles t = 2 mod 4
    half8 D0, D1;  float hD;   // tiles t = 3 mod 4

    // prologue: tiles 0,1,2 in flight (9 VMEM ops outstanding)
    ISSUE(A0, A1, hA, sb); sb += TILE_B;
    ISSUE(B0, B1, hB, sb); sb += TILE_B;
    ISSUE(C0, C1, hC, sb); sb += TILE_B;

    // main loop: t = 0,4,...,24; consumes tiles 0..27, issues through 30.
    for (int t = 0; t < 28; t += 4) {
        ISSUE(D0, D1, hD, sb); sb += TILE_B;   // tile t+3
        WAITC(9);                               // tile t complete
        VQ_STEP(A0, A1, hA, t);
        ISSUE(A0, A1, hA, sb); sb += TILE_B;   // tile t+4
        WAITC(9);                               // tile t+1 complete
        VQ_STEP(B0, B1, hB, t + 1);
        ISSUE(B0, B1, hB, sb); sb += TILE_B;   // tile t+5
        WAITC(9);                               // tile t+2 complete
        VQ_STEP(C0, C1, hC, t + 2);
        ISSUE(C0, C1, hC, sb); sb += TILE_B;   // tile t+6
        WAITC(9);                               // tile t+3 complete
        VQ_STEP(D0, D1, hD, t + 3);
    }
    // epilogue: issue tile 31 (set D), drain 28..31
    ISSUE(D0, D1, hD, sb);
    WAITC(9);
    VQ_STEP(A0, A1, hA, 28);
    WAITC(6);
    VQ_STEP(B0, B1, hB, 29);
    WAITC(3);
    VQ_STEP(C0, C1, hC, 30);
    WAITC(0);
    VQ_STEP(D0, D1, hD, 31);

    // recover codes; TOP-2 butterfly over the 16-lane column group
#pragma unroll
    for (int a = 0; a < 4; ++a)
#pragma unroll
        for (int r = 0; r < 4; ++r) {
            const unsigned b1 = __float_as_uint(best1[a][r]);
            const unsigned b2 = __float_as_uint(best2[a][r]);
            unsigned long long k1 = pack_key(best1[a][r], (int)(b1 & 31u) * TILE_C + cit);
            unsigned long long k2 = pack_key(best2[a][r], (int)(b2 & 31u) * TILE_C + cit);
#pragma unroll
            for (int off = 8; off; off >>= 1) {
                unsigned long long o1 = shfl_xor_u64_w16(k1, off);
                unsigned long long o2 = shfl_xor_u64_w16(k2, off);
                unsigned long long hi1 = (k1 > o1) ? k1 : o1;
                unsigned long long lo2 = (k2 < o2) ? k2 : o2;
                k1 = (k1 < o1) ? k1 : o1;
                k2 = (hi1 < lo2) ? hi1 : lo2;
            }
            if (m16 == 0) {
                kls[16 * a + g * 4 + r][wav]     = k1;
                kls[16 * a + g * 4 + r][4 + wav] = k2;
            }
        }
    __syncthreads();

    // merge 8 candidates per token (wave 0, one lane per token)
    if (tid < 64) {
        float ds[8]; int kk[8];
        unsigned long long kmin = ~0ULL;
#pragma unroll
        for (int w = 0; w < 8; ++w) {
            unsigned long long key = kls[tid][w];
            ds[w] = unpack_dist(key);
            kk[w] = (int)(unsigned)(key & 0xFFFFFFFFu);
            if (key < kmin) kmin = key;
        }
        int bk = (int)(unsigned)(kmin & 0xFFFFFFFFu);
        const float fmin = unpack_dist(kmin);
        int cnt = 0;
#pragma unroll
        for (int w = 0; w < 8; ++w) cnt += (ds[w] <= fmin + EPS_RESCORE) ? 1 : 0;

        if (cnt > 1) {   // near-tie in the coarse metric: exact fp32 rescore
            unsigned long long bkey = ~0ULL;   // smaller dist, tie smaller k
            const float* xr = x + (size_t)(t0 + tid) * D;
            for (int w = 0; w < 8; ++w) {
                if (ds[w] <= fmin + EPS_RESCORE) {
                    const int k = kk[w];
                    const float* cr = emb + (size_t)k * D;
                    float s0 = 0.f, s1 = 0.f, s2 = 0.f, s3 = 0.f;
#pragma unroll
                    for (int i = 0; i < 16; ++i) {
                        s0 = fmaf(cr[4 * i + 0], xr[4 * i + 0], s0);
                        s1 = fmaf(cr[4 * i + 1], xr[4 * i + 1], s1);
                        s2 = fmaf(cr[4 * i + 2], xr[4 * i + 2], s2);
                        s3 = fmaf(cr[4 * i + 3], xr[4 * i + 3], s3);
                    }
                    float hd = hnorm[k] - ((s0 + s1) + (s2 + s3));
                    unsigned long long key = pack_key(hd, k);
                    if (key < bkey) bkey = key;
                }
            }
            bk = (int)(unsigned)(bkey & 0xFFFFFFFFu);
        }
        bks[tid] = bk;
        out[IDX_OFF + t0 + tid] = (float)bk;
        atomicAdd(&counts[bk], 1u);
    }
    __syncthreads();

    // inline epilogue: quantize + sumsq (4 threads per token, coalesced)
    const int tok = tid >> 2;
    const int i4  = tid & 3;
    const int bk  = bks[tok];
    const float4* xr4 = (const float4*)(x + (size_t)(t0 + tok) * D);
    const float4* cr4 = (const float4*)(emb + (size_t)bk * D);
    float4* qr4 = (float4*)(out + (size_t)(t0 + tok) * D);
    float local = 0.f;
#pragma unroll
    for (int ii = 0; ii < 4; ++ii) {
        const int idx = i4 + 4 * ii;
        float4 xv = xr4[idx];
        float4 cv = cr4[idx];
        float dx = cv.x - xv.x, dy = cv.y - xv.y;
        float dz = cv.z - xv.z, dw = cv.w - xv.w;
        local += dx * dx + dy * dy + dz * dz + dw * dw;
        float4 q;
        q.x = xv.x + dx; q.y = xv.y + dy;   // straight-through: x + (q - x)
        q.z = xv.z + dz; q.w = xv.w + dw;
        qr4[idx] = q;
    }
    double ld = (double)local;
#pragma unroll
    for (int off = 32; off > 0; off >>= 1) ld += __shfl_down(ld, off, 64);
    if (lane == 0) wsum[wav] = ld;
    __syncthreads();
    if (tid == 0)
        blocksums[blockIdx.x] = (wsum[0] + wsum[1]) + (wsum[2] + wsum[3]);
}

__global__ __launch_bounds__(256) void vq_finalize(const unsigned* __restrict__ counts,
                                                   const double* __restrict__ blocksums,
                                                   float* __restrict__ out) {
    const int tid = threadIdx.x;
    double e = 0.0;
#pragma unroll
    for (int i = 0; i < 8; ++i) {
        int k = tid + i * 256;
        float p = (float)counts[k] / 65536.0f;
        out[PROB_OFF + k] = p;
        double pd = (double)p;
        e += pd * log(pd + 1e-5);
    }
    double s = 0.0;
#pragma unroll
    for (int i = 0; i < NBLK / 256; ++i) s += blocksums[tid + i * 256];
#pragma unroll
    for (int off = 32; off > 0; off >>= 1) {
        e += __shfl_down(e, off, 64);
        s += __shfl_down(s, off, 64);
    }
    __shared__ double we[4], ws2[4];
    int lane = tid & 63, wid = tid >> 6;
    if (lane == 0) { we[wid] = e; ws2[wid] = s; }
    __syncthreads();
    if (tid == 0) {
        double entropy = (we[0] + we[1]) + (we[2] + we[3]);
        double sumsq   = (ws2[0] + ws2[1]) + (ws2[2] + ws2[3]);
        double mse     = sumsq / (double)((size_t)N_TOK * D);
        out[SCAL_OFF + 0] = (float)(1.25 * mse + 0.1 * entropy); // vq_loss
        out[SCAL_OFF + 1] = (float)mse;                          // commitment_loss
        out[SCAL_OFF + 2] = (float)mse;                          // codebook_loss
        out[SCAL_OFF + 3] = (float)exp(-entropy);                // perplexity
        out[SCAL_OFF + 4] = (float)entropy;                      // entropy_loss
    }
}

extern "C" void kernel_launch(void* const* d_in, const int* in_sizes, int n_in,
                              void* d_out, int out_size, void* d_ws, size_t ws_size,
                              hipStream_t stream) {
    const float* x   = (const float*)d_in[0];
    const float* emb = (const float*)d_in[1];
    float* out = (float*)d_out;

    char* ws = (char*)d_ws;
    float*    hnorm     = (float*)(ws + WS_HNORM);
    unsigned* counts    = (unsigned*)(ws + WS_COUNT);
    double*   blocksums = (double*)(ws + WS_BSUM);
    char*     swb       = ws + WS_SW;

    vq_init<<<K * 8 / 256, 256, 0, stream>>>(emb, hnorm, counts, blocksums, swb);
    vq_fused<<<NBLK, 256, 0, stream>>>(x, emb, hnorm, swb, counts, blocksums, out);
    vq_finalize<<<1, 256, 0, stream>>>(counts, blocksums, out);
}

// Round 15
// 123.223 us; speedup vs baseline: 1.1354x; 1.0467x over previous
//
#include <hip/hip_runtime.h>
#include <float.h>

typedef _Float16 half8 __attribute__((ext_vector_type(8)));
typedef float    f32x4 __attribute__((ext_vector_type(4)));

// Problem constants
constexpr int N_TOK = 65536;        // 16*64*64 tokens
constexpr int D     = 64;           // embedding dim
constexpr int K     = 2048;         // codebook size
constexpr int TILE_C = 64;          // codes per tile
constexpr int NTILE  = K / TILE_C;  // 32
constexpr int TOK_PER_BLK = 64;     // tokens per fused block
constexpr int NBLK = N_TOK / TOK_PER_BLK;    // 1024 fused blocks
// hh-only coarse distances: err ~ sigma 3.2e-3; belt 0.15 ~ 47 sigma.
constexpr float EPS_RESCORE = 0.15f;

// Output layout (all float32, concatenated in reference return order)
constexpr size_t QN       = (size_t)N_TOK * D;
constexpr size_t SCAL_OFF = QN;
constexpr size_t IDX_OFF  = QN + 5;
constexpr size_t PROB_OFF = IDX_OFF + N_TOK;

// Workspace layout (bytes), total ~352 KB
constexpr size_t WS_HNORM = 0;                          // [K] f32  0.5*||c||^2
constexpr size_t WS_COUNT = 8192;                       // [K] u32
constexpr size_t WS_BSUM  = 16384;                      // [1024] double
constexpr size_t WS_SW    = 24576;                      // [NTILE][256 rec][40 B] hi-frag records
constexpr int REC_B  = 40;                              // 2x half8 (hi) + f32 hnorm + 4 pad
constexpr int TILE_B = 256 * REC_B;                     // 10240 B per tile

__device__ inline unsigned long long pack_key(float d, int k) {
    unsigned u = __float_as_uint(d);
    u = (u & 0x80000000u) ? ~u : (u | 0x80000000u);   // monotone float->uint
    return ((unsigned long long)u << 32) | (unsigned)k;
}

__device__ inline float unpack_dist(unsigned long long key) {
    unsigned u = (unsigned)(key >> 32);
    u = (u & 0x80000000u) ? (u & 0x7FFFFFFFu) : ~u;   // inverse monotone map
    return __uint_as_float(u);
}

__device__ inline unsigned long long shfl_xor_u64_w16(unsigned long long v, int m) {
    int lo = __shfl_xor((int)(unsigned)v, m, 16);
    int hi = __shfl_xor((int)(unsigned)(v >> 32), m, 16);
    return ((unsigned long long)(unsigned)hi << 32) | (unsigned)lo;
}

// One thread per (code row r, 8-elem chunk c0). 40-B record per (tile,
// consumer tid): {hi chunk g, hi chunk g+4, hnorm(f32), pad}. Consumer
// tid = w*64+l (g=l>>4, m16=l&15, code = t*64 + w*16 + m16). Producer
// (r,c0): lane=(c0&3)*16+m16, slot=c0>>2; c0<4 thread writes hn after the
// 8-way butterfly.
__global__ __launch_bounds__(256) void vq_init(const float* __restrict__ emb,
                                               float* __restrict__ hnorm,
                                               unsigned* __restrict__ counts,
                                               double* __restrict__ blocksums,
                                               char* __restrict__ swb) {
    const int g  = blockIdx.x * 256 + threadIdx.x;   // 0..16383
    const int r  = g >> 3;                           // code row
    const int c0 = g & 7;                            // chunk within row
    const float4* p4 = (const float4*)(emb + (size_t)r * D + 8 * c0);
    float4 q0 = p4[0], q1 = p4[1];
    float v[8] = {q0.x, q0.y, q0.z, q0.w, q1.x, q1.y, q1.z, q1.w};
    half8 h;
    float s = 0.f;
#pragma unroll
    for (int i = 0; i < 8; ++i) {
        s += v[i] * v[i];
        h[i] = (_Float16)v[i];
    }
    const int t    = r >> 6;
    const int w    = (r >> 4) & 3;
    const int m16  = r & 15;
    const int lane = (c0 & 3) * 16 + m16;
    const int slot = c0 >> 2;
    char* rec = swb + (size_t)(t * 256 + w * 64 + lane) * REC_B;
    *(half8*)(rec + slot * 16) = h;   // hi fragment (P0 or P1)

#pragma unroll
    for (int off = 1; off < 8; off <<= 1) s += __shfl_xor(s, off, 8);
    if (c0 < 4) *(float*)(rec + 32) = 0.5f * s;   // per-record hnorm
    if (c0 == 0) hnorm[r] = 0.5f * s;             // global (rescore path)
    if (g < K) counts[g] = 0u;
    if (g < NBLK) blocksums[g] = 0.0;
}

// PINNED tile load, saddr form: fixed per-lane voffset (tid*40), uniform
// SGPR base advanced via SALU. asm volatile cannot be sunk (R12-proven).
#define ISSUE(P0, P1, HN, SB)                                                      \
  asm volatile("global_load_dwordx4 %0, %3, %4\n\t"                                \
               "global_load_dwordx4 %1, %3, %4 offset:16\n\t"                      \
               "global_load_dword   %2, %3, %4 offset:32"                          \
               : "=&v"(P0), "=&v"(P1), "=&v"(HN)                                   \
               : "v"(voff), "s"(SB));

// Counted wait (never 0 in main loop) + sched_barrier (rule #18).
#define WAITC(N)                                                                   \
  asm volatile("s_waitcnt vmcnt(" #N ")" ::: "memory");                            \
  __builtin_amdgcn_sched_barrier(0);

// MFMA half of a step: 8 MFMAs into bank ACC, C-input of the first MFMA is
// the shared hnv broadcast (4 movs/step, was 16). NO dependent VALU here --
// the compare for this tile runs one region later (software-pipelined), so
// each region's compare ops are independent of its own MFMA results and the
// VALU pipe fills the matrix-pipe shadow instead of serializing behind it.
#define VQ_MFMA(P0, P1, HN, ACC)                                                   \
  {                                                                                \
    f32x4 _hv = {(HN), (HN), (HN), (HN)};                                          \
    _Pragma("unroll")                                                              \
    for (int a = 0; a < 4; ++a) {                                                  \
      ACC[a] = __builtin_amdgcn_mfma_f32_16x16x32_f16(axh[a][0], P0, _hv, 0, 0, 0);    \
      ACC[a] = __builtin_amdgcn_mfma_f32_16x16x32_f16(axh[a][1], P1, ACC[a], 0, 0, 0); \
    }                                                                              \
  }

// Compare half (for the PREVIOUS region's bank): top-2 via fmed3 (3 VALU/val).
// Tile idx packed in the 5 low mantissa bits (<=32 ulp ~ 4.9e-4 << belt).
#define VQ_CMP(ACC, TT)                                                            \
    _Pragma("unroll")                                                              \
    for (int a = 0; a < 4; ++a)                                                    \
      _Pragma("unroll")                                                            \
      for (int r = 0; r < 4; ++r) {                                                \
        unsigned _kb = (__float_as_uint(ACC[a][r]) & 0xFFFFFFE0u) | (unsigned)(TT);\
        float _f = __uint_as_float(_kb);                                           \
        best2[a][r] = __builtin_amdgcn_fmed3f(best1[a][r], best2[a][r], _f);       \
        best1[a][r] = fminf(best1[a][r], _f);                                      \
      }

// Fused: one block = 64 tokens x ALL 2048 codes. hh-only coarse scan,
// asm-pinned depth-3 pipeline, and a 1-tile SOFTWARE-PIPELINED compare:
// region t = {ISSUE(t+3); WAITC(9); MFMA(t)->bank; CMP(t-1, other bank)}.
// Acc banks alternate even/odd tile (named arrays, compile-time indices).
__global__ __launch_bounds__(256, 2) void vq_fused(const float* __restrict__ x,
                                                   const float* __restrict__ emb,
                                                   const float* __restrict__ hnorm,
                                                   const char* __restrict__ swb,
                                                   unsigned* __restrict__ counts,
                                                   double* __restrict__ blocksums,
                                                   float* __restrict__ out) {
    __shared__ unsigned long long kls[64][10];        // 8 candidates + pad
    __shared__ int bks[64];
    __shared__ double wsum[4];

    const int tid  = threadIdx.x;
    const int lane = tid & 63;
    const int wav  = tid >> 6;
    const int t0   = blockIdx.x * TOK_PER_BLK;
    const int m16  = lane & 15;             // A row (token) / B col (code)
    const int g    = lane >> 4;             // k-chunk group (0..3)
    const int ko   = g * 8;
    const int cit  = wav * 16 + m16;        // wave w owns codes [w*16, w*16+16)

    // A fragments: 4 a-tiles, hi (negated fp16) only
    half8 axh[4][2];
#pragma unroll
    for (int a = 0; a < 4; ++a) {
        const float* xr = x + (size_t)(t0 + 16 * a + m16) * D;
#pragma unroll
        for (int c = 0; c < 2; ++c) {
            const float4* p4 = (const float4*)(xr + 32 * c + ko);
            float4 q0 = p4[0], q1 = p4[1];
            float v[8] = {q0.x, q0.y, q0.z, q0.w, q1.x, q1.y, q1.z, q1.w};
            half8 h;
#pragma unroll
            for (int j = 0; j < 8; ++j) h[j] = (_Float16)(-v[j]);
            axh[a][c] = h;
        }
    }

    float best1[4][4], best2[4][4];         // packed keys, top-2 per lane
#pragma unroll
    for (int a = 0; a < 4; ++a)
#pragma unroll
        for (int r = 0; r < 4; ++r) { best1[a][r] = FLT_MAX; best2[a][r] = FLT_MAX; }

    // fixed per-lane offset + uniform SGPR tile base (advances via SALU)
    const unsigned voff = (unsigned)(tid * REC_B);
    unsigned long long sb = (unsigned long long)swb;

    half8 A0, A1;  float hA;   // set for tiles t = 0 mod 4
    half8 B0, B1;  float hB;   // set for tiles t = 1 mod 4
    half8 C0, C1;  float hC;   // set for tiles t = 2 mod 4
    half8 D0, D1;  float hD;   // set for tiles t = 3 mod 4
    f32x4 accE[4], accO[4];    // acc banks: even / odd tiles

    // prologue: tiles 0,1,2 in flight (9 VMEM ops outstanding)
    ISSUE(A0, A1, hA, sb); sb += TILE_B;
    ISSUE(B0, B1, hB, sb); sb += TILE_B;
    ISSUE(C0, C1, hC, sb); sb += TILE_B;

    // region 0: tile 0 (set A, bank E); no compare yet
    ISSUE(D0, D1, hD, sb); sb += TILE_B;    // tile 3
    WAITC(9);                                // tile 0 complete
    VQ_MFMA(A0, A1, hA, accE);

    // regions 1..28 (7 x 4): MFMA(tile t) + CMP(tile t-1)
    for (int t = 1; t < 26; t += 4) {
        ISSUE(A0, A1, hA, sb); sb += TILE_B;   // tile t+3
        WAITC(9);                               // tile t complete
        VQ_MFMA(B0, B1, hB, accO);
        VQ_CMP(accE, t - 1);
        ISSUE(B0, B1, hB, sb); sb += TILE_B;   // tile t+4
        WAITC(9);                               // tile t+1 complete
        VQ_MFMA(C0, C1, hC, accE);
        VQ_CMP(accO, t);
        ISSUE(C0, C1, hC, sb); sb += TILE_B;   // tile t+5
        WAITC(9);                               // tile t+2 complete
        VQ_MFMA(D0, D1, hD, accO);
        VQ_CMP(accE, t + 1);
        ISSUE(D0, D1, hD, sb); sb += TILE_B;   // tile t+6
        WAITC(9);                               // tile t+3 complete
        VQ_MFMA(A0, A1, hA, accE);
        VQ_CMP(accO, t + 2);
    }
    // after loop: MFMA'd tiles 0..28, compared 0..27, issued 0..31.
    // region 29: tile 29 (set B, bank O), cmp 28 (E)
    WAITC(6);
    VQ_MFMA(B0, B1, hB, accO);
    VQ_CMP(accE, 28);
    // region 30: tile 30 (set C, bank E), cmp 29 (O)
    WAITC(3);
    VQ_MFMA(C0, C1, hC, accE);
    VQ_CMP(accO, 29);
    // region 31: tile 31 (set D, bank O), cmp 30 (E)
    WAITC(0);
    VQ_MFMA(D0, D1, hD, accO);
    VQ_CMP(accE, 30);
    // final compare for tile 31
    VQ_CMP(accO, 31);

    // recover codes; TOP-2 butterfly over the 16-lane column group
#pragma unroll
    for (int a = 0; a < 4; ++a)
#pragma unroll
        for (int r = 0; r < 4; ++r) {
            const unsigned b1 = __float_as_uint(best1[a][r]);
            const unsigned b2 = __float_as_uint(best2[a][r]);
            unsigned long long k1 = pack_key(best1[a][r], (int)(b1 & 31u) * TILE_C + cit);
            unsigned long long k2 = pack_key(best2[a][r], (int)(b2 & 31u) * TILE_C + cit);
#pragma unroll
            for (int off = 8; off; off >>= 1) {
                unsigned long long o1 = shfl_xor_u64_w16(k1, off);
                unsigned long long o2 = shfl_xor_u64_w16(k2, off);
                unsigned long long hi1 = (k1 > o1) ? k1 : o1;
                unsigned long long lo2 = (k2 < o2) ? k2 : o2;
                k1 = (k1 < o1) ? k1 : o1;
                k2 = (hi1 < lo2) ? hi1 : lo2;
            }
            if (m16 == 0) {
                kls[16 * a + g * 4 + r][wav]     = k1;
                kls[16 * a + g * 4 + r][4 + wav] = k2;
            }
        }
    __syncthreads();

    // merge 8 candidates per token (wave 0, one lane per token)
    if (tid < 64) {
        float ds[8]; int kk[8];
        unsigned long long kmin = ~0ULL;
#pragma unroll
        for (int w = 0; w < 8; ++w) {
            unsigned long long key = kls[tid][w];
            ds[w] = unpack_dist(key);
            kk[w] = (int)(unsigned)(key & 0xFFFFFFFFu);
            if (key < kmin) kmin = key;
        }
        int bk = (int)(unsigned)(kmin & 0xFFFFFFFFu);
        const float fmin = unpack_dist(kmin);
        int cnt = 0;
#pragma unroll
        for (int w = 0; w < 8; ++w) cnt += (ds[w] <= fmin + EPS_RESCORE) ? 1 : 0;

        if (cnt > 1) {   // near-tie in the coarse metric: exact fp32 rescore
            unsigned long long bkey = ~0ULL;   // smaller dist, tie smaller k
            const float* xr = x + (size_t)(t0 + tid) * D;
            for (int w = 0; w < 8; ++w) {
                if (ds[w] <= fmin + EPS_RESCORE) {
                    const int k = kk[w];
                    const float* cr = emb + (size_t)k * D;
                    float s0 = 0.f, s1 = 0.f, s2 = 0.f, s3 = 0.f;
#pragma unroll
                    for (int i = 0; i < 16; ++i) {
                        s0 = fmaf(cr[4 * i + 0], xr[4 * i + 0], s0);
                        s1 = fmaf(cr[4 * i + 1], xr[4 * i + 1], s1);
                        s2 = fmaf(cr[4 * i + 2], xr[4 * i + 2], s2);
                        s3 = fmaf(cr[4 * i + 3], xr[4 * i + 3], s3);
                    }
                    float hd = hnorm[k] - ((s0 + s1) + (s2 + s3));
                    unsigned long long key = pack_key(hd, k);
                    if (key < bkey) bkey = key;
                }
            }
            bk = (int)(unsigned)(bkey & 0xFFFFFFFFu);
        }
        bks[tid] = bk;
        out[IDX_OFF + t0 + tid] = (float)bk;
        atomicAdd(&counts[bk], 1u);
    }
    __syncthreads();

    // inline epilogue: quantize + sumsq (4 threads per token, coalesced)
    const int tok = tid >> 2;
    const int i4  = tid & 3;
    const int bk  = bks[tok];
    const float4* xr4 = (const float4*)(x + (size_t)(t0 + tok) * D);
    const float4* cr4 = (const float4*)(emb + (size_t)bk * D);
    float4* qr4 = (float4*)(out + (size_t)(t0 + tok) * D);
    float local = 0.f;
#pragma unroll
    for (int ii = 0; ii < 4; ++ii) {
        const int idx = i4 + 4 * ii;
        float4 xv = xr4[idx];
        float4 cv = cr4[idx];
        float dx = cv.x - xv.x, dy = cv.y - xv.y;
        float dz = cv.z - xv.z, dw = cv.w - xv.w;
        local += dx * dx + dy * dy + dz * dz + dw * dw;
        float4 q;
        q.x = xv.x + dx; q.y = xv.y + dy;   // straight-through: x + (q - x)
        q.z = xv.z + dz; q.w = xv.w + dw;
        qr4[idx] = q;
    }
    double ld = (double)local;
#pragma unroll
    for (int off = 32; off > 0; off >>= 1) ld += __shfl_down(ld, off, 64);
    if (lane == 0) wsum[wav] = ld;
    __syncthreads();
    if (tid == 0)
        blocksums[blockIdx.x] = (wsum[0] + wsum[1]) + (wsum[2] + wsum[3]);
}

__global__ __launch_bounds__(256) void vq_finalize(const unsigned* __restrict__ counts,
                                                   const double* __restrict__ blocksums,
                                                   float* __restrict__ out) {
    const int tid = threadIdx.x;
    double e = 0.0;
#pragma unroll
    for (int i = 0; i < 8; ++i) {
        int k = tid + i * 256;
        float p = (float)counts[k] / 65536.0f;
        out[PROB_OFF + k] = p;
        double pd = (double)p;
        e += pd * log(pd + 1e-5);
    }
    double s = 0.0;
#pragma unroll
    for (int i = 0; i < NBLK / 256; ++i) s += blocksums[tid + i * 256];
#pragma unroll
    for (int off = 32; off > 0; off >>= 1) {
        e += __shfl_down(e, off, 64);
        s += __shfl_down(s, off, 64);
    }
    __shared__ double we[4], ws2[4];
    int lane = tid & 63, wid = tid >> 6;
    if (lane == 0) { we[wid] = e; ws2[wid] = s; }
    __syncthreads();
    if (tid == 0) {
        double entropy = (we[0] + we[1]) + (we[2] + we[3]);
        double sumsq   = (ws2[0] + ws2[1]) + (ws2[2] + ws2[3]);
        double mse     = sumsq / (double)((size_t)N_TOK * D);
        out[SCAL_OFF + 0] = (float)(1.25 * mse + 0.1 * entropy); // vq_loss
        out[SCAL_OFF + 1] = (float)mse;                          // commitment_loss
        out[SCAL_OFF + 2] = (float)mse;                          // codebook_loss
        out[SCAL_OFF + 3] = (float)exp(-entropy);                // perplexity
        out[SCAL_OFF + 4] = (float)entropy;                      // entropy_loss
    }
}

extern "C" void kernel_launch(void* const* d_in, const int* in_sizes, int n_in,
                              void* d_out, int out_size, void* d_ws, size_t ws_size,
                              hipStream_t stream) {
    const float* x   = (const float*)d_in[0];
    const float* emb = (const float*)d_in[1];
    float* out = (float*)d_out;

    char* ws = (char*)d_ws;
    float*    hnorm     = (float*)(ws + WS_HNORM);
    unsigned* counts    = (unsigned*)(ws + WS_COUNT);
    double*   blocksums = (double*)(ws + WS_BSUM);
    char*     swb       = ws + WS_SW;

    vq_init<<<K * 8 / 256, 256, 0, stream>>>(emb, hnorm, counts, blocksums, swb);
    vq_fused<<<NBLK, 256, 0, stream>>>(x, emb, hnorm, swb, counts, blocksums, out);
    vq_finalize<<<1, 256, 0, stream>>>(counts, blocksums, out);
}